// Round 1
// 85.155 us; speedup vs baseline: 1.0492x; 1.0492x over previous
//
#include <hip/hip_runtime.h>

#define CIN  32
#define OCH  64
#define HH   56
#define WW   56
#define BB   4
#define OT   4                  // output channels per thread/block
#define IMG  (HH * WW)          // 3136
#define NW   18432              // 64*32*3*3
#define PH   58
#define PW   58
#define PIMG (PH * PW)          // 3364 padded image
#define NPAD (BB * CIN * PIMG)  // 430592 padded elements
#define PADBLKS (NPAD / 256)    // 1682 (exact)
#define XOFF 64                 // padded x starts at ws + 64 floats (256B aligned)

typedef float vf2 __attribute__((ext_vector_type(2)));  // -> v_pk_add_f32

// One dispatch does BOTH jobs:
//   blocks 0..1681 : write zero-padded (B,C,58,58) copy of x into ws+XOFF
//   block  1682    : |w| mean -> ws[0]  (single block, plain store, no atomic/memset)
__global__ __launch_bounds__(256) void prep(const float* __restrict__ x,
                                            const float* __restrict__ w,
                                            float* __restrict__ ws) {
    if (blockIdx.x == PADBLKS) {
        // 18432 weights = 256 threads * 18 float4, coalesced
        float s = 0.f;
        const float4* w4 = reinterpret_cast<const float4*>(w);
        #pragma unroll
        for (int k = 0; k < 18; ++k) {
            float4 v = w4[k * 256 + threadIdx.x];
            s += fabsf(v.x) + fabsf(v.y) + fabsf(v.z) + fabsf(v.w);
        }
        #pragma unroll
        for (int off = 32; off; off >>= 1) s += __shfl_down(s, off);
        __shared__ float sm[4];
        if ((threadIdx.x & 63) == 0) sm[threadIdx.x >> 6] = s;
        __syncthreads();
        if (threadIdx.x == 0)
            ws[0] = (sm[0] + sm[1] + sm[2] + sm[3]) * (1.0f / (float)NW);
        return;
    }
    int idx = blockIdx.x * 256 + threadIdx.x;          // 0..NPAD-1
    int bc  = idx / PIMG;
    int r   = idx - bc * PIMG;
    int ph  = r / PW;
    int pw  = r - ph * PW;
    int hh  = ph - 1, wc = pw - 1;
    float v = 0.f;
    if ((unsigned)hh < (unsigned)HH && (unsigned)wc < (unsigned)WW)
        v = x[bc * IMG + hh * WW + wc];                // coalesced within rows
    ws[XOFF + idx] = v;
}

// block = 64 threads (1 wave) covering 64 pixels of one (b, o-tile).
// Padded input => no masks, no clamps: tap (c,kh,kw) = xb[c*PIMG + kh*PW + kw].
__global__ __launch_bounds__(64) void minconv_kernel(const float* __restrict__ ws,
                                                     const float* __restrict__ wts,
                                                     float* __restrict__ out) {
    const float* xp = ws + XOFF;
    const int hw = blockIdx.x * 64 + threadIdx.x;      // 0..3135 exact
    const int o0 = blockIdx.y * OT;
    const int b  = blockIdx.z;
    const int h  = hw / WW;
    const int w  = hw - h * WW;

    // padded coords of tap (kh,kw) for output (h,w): (h+kh, w+kw)
    const float* xb = xp + (size_t)b * (CIN * PIMG) + h * PW + w;   // block/lane base
    const float* wb = wts + o0 * (CIN * 9);            // wave-uniform -> s_load

    vf2   a0[OT], a1[OT], a2[OT], a3[OT];              // paired accumulators
    float a8[OT];
    #pragma unroll
    for (int oo = 0; oo < OT; ++oo) {
        a0[oo] = (vf2)(0.f); a1[oo] = (vf2)(0.f);
        a2[oo] = (vf2)(0.f); a3[oo] = (vf2)(0.f);
        a8[oo] = 0.f;
    }

    #pragma unroll 2
    for (int c = 0; c < CIN; ++c) {
        float xv[9];
        #pragma unroll
        for (int kh = 0; kh < 3; ++kh)
            #pragma unroll
            for (int kw = 0; kw < 3; ++kw)
                xv[kh * 3 + kw] = xb[c * PIMG + kh * PW + kw];
        #pragma unroll
        for (int oo = 0; oo < OT; ++oo) {
            const float* wp = wb + oo * (CIN * 9) + c * 9;   // uniform -> s_load
            vf2 m;
            m.x = fminf(xv[0], wp[0]); m.y = fminf(xv[1], wp[1]); a0[oo] += m;
            m.x = fminf(xv[2], wp[2]); m.y = fminf(xv[3], wp[3]); a1[oo] += m;
            m.x = fminf(xv[4], wp[4]); m.y = fminf(xv[5], wp[5]); a2[oo] += m;
            m.x = fminf(xv[6], wp[6]); m.y = fminf(xv[7], wp[7]); a3[oo] += m;
            a8[oo] += fminf(xv[8], wp[8]);
        }
    }

    const float mu = ws[0];                            // already / NW
    float* ob = out + ((size_t)b * OCH + o0) * IMG + hw;
    #pragma unroll
    for (int oo = 0; oo < OT; ++oo) {
        vf2 s2 = (a0[oo] + a1[oo]) + (a2[oo] + a3[oo]);
        ob[oo * IMG] = mu * (s2.x + s2.y + a8[oo]);
    }
}

extern "C" void kernel_launch(void* const* d_in, const int* in_sizes, int n_in,
                              void* d_out, int out_size, void* d_ws, size_t ws_size,
                              hipStream_t stream) {
    const float* x   = (const float*)d_in[0];   // 4*32*56*56
    const float* w   = (const float*)d_in[1];   // 64*32*3*3
    float*       out = (float*)d_out;           // 4*64*56*56
    float*       ws  = (float*)d_ws;

    prep<<<PADBLKS + 1, 256, 0, stream>>>(x, w, ws);
    dim3 grid(IMG / 64, OCH / OT, BB);          // 49 x 16 x 4 = 3136 blocks
    minconv_kernel<<<grid, 64, 0, stream>>>(ws, w, out);
}